// Round 17
// baseline (470.679 us; speedup 1.0000x reference)
//
#include <hip/hip_runtime.h>
#include <math.h>

namespace {

constexpr int T = 5, N = 2048, K = 20, E = 512;
constexpr int H = 64, U = 8;
constexpr int CAP = 512;           // max neighbors kept (measured mean ~103)
constexpr float SLOPE = 0.01f;

typedef __attribute__((ext_vector_type(8))) short short8;
typedef __attribute__((ext_vector_type(4))) float f32x4;

__device__ inline float sigm(float x) { return 1.0f / (1.0f + expf(-x)); }

// split fp32 -> bf16 hi + bf16 lo (truncation; x ~= hi+lo with rel err <= 2^-16)
__device__ inline void bsplit(float x, short& hi, short& lo) {
  unsigned u = __float_as_uint(x);
  hi = (short)(u >> 16);
  float r = x - __uint_as_float(u & 0xFFFF0000u);
  lo = (short)(__float_as_uint(r) >> 16);
}

__device__ inline float rdlane(float v, int lane) {
  return __int_as_float(__builtin_amdgcn_readlane(__float_as_int(v), lane));
}

// 512-col fragment pack ([U][Ksz][64] -> hi-only fragment blocks, BK=64)
__device__ inline void pack512(const float* __restrict__ src, short* __restrict__ dst,
                               const int Ksz, const int pb, const int nPB) {
  const int nb64 = Ksz >> 6;
  const int total = 8 * Ksz * 64;
  for (int idx = threadIdx.x + pb * 256; idx < total; idx += 256 * nPB) {
    const int u = idx / (Ksz * 64), rem = idx - u * Ksz * 64;
    const int f = rem >> 6, o = rem & 63;
    const int col = u * 64 + o;
    const long base = ((long)(col >> 7) * nb64 + (f >> 6)) * 8192
                    + (((f >> 5) & 1) * 8 + ((col >> 4) & 7)) * 512
                    + ((f >> 3) & 3) * 128 + (col & 15) * 8 + (f & 7);
    dst[base] = (short)(__float_as_uint(src[idx]) >> 16);
  }
}

// ---------------- mega-prep: compact (512) + packs (128) + p-GRU (512) ----------
__global__ __launch_bounds__(256) void k_prep_all(
    const float* __restrict__ WihM, const float* __restrict__ WhhM,
    const float* __restrict__ WihS, const float* __restrict__ WhhS,
    const float* __restrict__ WhhP, const float* __restrict__ Wb,
    const float* __restrict__ g1W, const float* __restrict__ g2W,
    const float* __restrict__ adj,
    const float* __restrict__ p, const float* __restrict__ WihP,
    const float* __restrict__ bihP, const float* __restrict__ bhhP,
    short* __restrict__ BfM, short* __restrict__ BfS,
    short* __restrict__ Bf1, short* __restrict__ Bf2,
    float* __restrict__ WhhTm, float* __restrict__ WhhTs,
    float* __restrict__ Wt2, int* __restrict__ nbr, int* __restrict__ deg,
    float* __restrict__ q)
{
  const int b = blockIdx.x;
  if (b < N / 4) {
    const int w = threadIdx.x >> 6, lane = threadIdx.x & 63;
    const int i = b * 4 + w;
    int base = 0;
    for (int j0 = 0; j0 < N; j0 += 64) {
      const float v = adj[(long)i * N + j0 + lane];
      const unsigned long long mask = __ballot(v > 0.f);
      const int pre = __popcll(mask & ((1ull << lane) - 1ull));
      if (v > 0.f && base + pre < CAP) nbr[i * CAP + base + pre] = j0 + lane;
      base += __popcll(mask);
    }
    if (lane == 0) deg[i] = base < CAP ? base : CAP;
    return;
  }
  if (b < N / 4 + 128) {
    const int pb = b - N / 4;        // 0..127
    constexpr int NPB = 128;
    for (int idx = threadIdx.x + pb * 256; idx < 192 * 512; idx += 256 * NPB) {
      const int o = idx >> 9, k = idx & 511;
      const long base = (long)(k >> 6) * 12288 + (((k >> 5) & 1) * 12 + (o >> 4)) * 512
                      + ((k >> 3) & 3) * 128 + (o & 15) * 8 + (k & 7);
      BfM[base] = (short)(__float_as_uint(WihM[idx]) >> 16);
    }
    for (int idx = threadIdx.x + pb * 256; idx < 192 * 64; idx += 256 * NPB) {
      const int o = idx >> 6, k = idx & 63;
      const long base = (((k >> 5) & 1) * 12 + (o >> 4)) * 512
                      + ((k >> 3) & 3) * 128 + (o & 15) * 8 + (k & 7);
      BfS[base] = (short)(__float_as_uint(WihS[idx]) >> 16);
    }
    for (int idx = threadIdx.x + pb * 256; idx < 64 * 192; idx += 256 * NPB) {
      const int k2 = idx / 192, row = idx % 192;
      WhhTm[idx] = WhhM[row * 64 + k2];
      WhhTs[idx] = WhhS[row * 64 + k2];
    }
    for (int idx = threadIdx.x + pb * 256; idx < 64 * 64 * 64; idx += 256 * NPB) {
      const int o = idx >> 12, rem = idx & 4095, i = rem >> 6, j = rem & 63;
      Wt2[((i * 16 + (j >> 2)) * 64 + o) * 4 + (j & 3)] = Wb[(o * 64 + i) * 64 + j];
    }
    pack512(g1W, Bf1, 64, pb, NPB);
    pack512(g2W, Bf2, 512, pb, NPB);
    return;
  }
  // p-GRU: 4 seqs per block, Whh rows read directly (per-lane contiguous)
  const int rb = b - (N / 4 + 128);
  const int w = threadIdx.x >> 6, l = threadIdx.x & 63;
  const int n = rb * 4 + w;
  float wr[64], wz[64], wn[64];
  #pragma unroll
  for (int k2 = 0; k2 < 64; ++k2) {
    wr[k2] = WhhP[l * 64 + k2];
    wz[k2] = WhhP[(64 + l) * 64 + k2];
    wn[k2] = WhhP[(128 + l) * 64 + k2];
  }
  float iR[3], iZ[3], iN[3];
  #pragma unroll
  for (int c = 0; c < 3; ++c) {
    iR[c] = WihP[l * 3 + c];
    iZ[c] = WihP[(64 + l) * 3 + c];
    iN[c] = WihP[(128 + l) * 3 + c];
  }
  const float biR = bihP[l], biZ = bihP[64 + l], biN = bihP[128 + l];
  const float bhR = bhhP[l], bhZ = bhhP[64 + l], bhN = bhhP[128 + l];
  float h = 0.f, qs = 0.f;
  for (int t = 0; t < T; ++t) {
    const float x0 = p[n * 15 + t * 3], x1 = p[n * 15 + t * 3 + 1], x2 = p[n * 15 + t * 3 + 2];
    const float gR = biR + iR[0] * x0 + iR[1] * x1 + iR[2] * x2;
    const float gZ = biZ + iZ[0] * x0 + iZ[1] * x1 + iZ[2] * x2;
    const float gN = biN + iN[0] * x0 + iN[1] * x1 + iN[2] * x2;
    float aR = bhR, aZ = bhZ, aN = bhN;
    #pragma unroll
    for (int k2 = 0; k2 < 64; ++k2) {
      const float hk = rdlane(h, k2);
      aR += wr[k2] * hk; aZ += wz[k2] * hk; aN += wn[k2] * hk;
    }
    const float r = sigm(gR + aR), z = sigm(gZ + aZ);
    const float nn = tanhf(gN + r * aN);
    h = (1.f - z) * nn + z * h;
    qs += h;
  }
  q[n * H + l] = qs;
}

// ---------------- 192-col GEMM: [rows,Ksz] x [Ksz,192] + bias, 2-pass -----------
// C = (Ah+Al)·Bh. BK=64 B-dbuf + A raw-float4 prefetch (bsplit at use).
__global__ __launch_bounds__(256, 2) void k_gemm(
    const float* __restrict__ A, const short* __restrict__ Bf,
    const float* __restrict__ bias, float* __restrict__ out,
    const long row0, const int nb, const int strideA)
{
  __shared__ alignas(16) short Bc[2][24 * 512];   // 2 x 24 KB
  const int tid = threadIdx.x, w = tid >> 6, l = tid & 63;
  const int lr = l & 15, g = l >> 4;
  const long blkrow = (long)blockIdx.x * 128;

  f32x4 acc[2][12];
  #pragma unroll
  for (int mf = 0; mf < 2; ++mf)
    #pragma unroll
    for (int nt = 0; nt < 12; ++nt) acc[mf][nt] = (f32x4){0.f, 0.f, 0.f, 0.f};

  float4 pf[2][2][2];   // [kc][mf][half] raw A prefetch

  auto LOADA = [&](int b) {
    #pragma unroll
    for (int kc = 0; kc < 2; ++kc)
      #pragma unroll
      for (int mf = 0; mf < 2; ++mf) {
        const long r = blkrow + w * 32 + mf * 16 + lr;
        const float* __restrict__ src = A + (row0 + r) * (long)strideA + b * 64 + kc * 32 + g * 8;
        pf[kc][mf][0] = *reinterpret_cast<const float4*>(src);
        pf[kc][mf][1] = *reinterpret_cast<const float4*>(src + 4);
      }
  };
  auto STAGE = [&](int buf, int b) {
    const short* __restrict__ bsrc = Bf + (long)b * 12288;
    #pragma unroll
    for (int i = 0; i < 6; ++i) {
      const int c = w + i * 4;      // 24 x 1KB chunks
      __builtin_amdgcn_global_load_lds(
          (const __attribute__((address_space(1))) void*)(bsrc + c * 512 + l * 8),
          (__attribute__((address_space(3))) void*)(&Bc[buf][c * 512]), 16, 0, 0);
    }
  };

  STAGE(0, 0);
  LOADA(0);
  __syncthreads();

  for (int b = 0; b < nb; ++b) {
    const bool more = (b + 1 < nb);
    if (more) STAGE((b + 1) & 1, b + 1);
    // convert current prefetch to fragments, then immediately issue next loads
    short8 ah[2][2], al[2][2];
    #pragma unroll
    for (int kc = 0; kc < 2; ++kc)
      #pragma unroll
      for (int mf = 0; mf < 2; ++mf) {
        const float4 v0 = pf[kc][mf][0], v1 = pf[kc][mf][1];
        short h0,l0,h1,l1,h2,l2,h3,l3,h4,l4,h5,l5,h6,l6,h7,l7;
        bsplit(v0.x,h0,l0); bsplit(v0.y,h1,l1); bsplit(v0.z,h2,l2); bsplit(v0.w,h3,l3);
        bsplit(v1.x,h4,l4); bsplit(v1.y,h5,l5); bsplit(v1.z,h6,l6); bsplit(v1.w,h7,l7);
        ah[kc][mf] = (short8){h0,h1,h2,h3,h4,h5,h6,h7};
        al[kc][mf] = (short8){l0,l1,l2,l3,l4,l5,l6,l7};
      }
    if (more) LOADA(b + 1);
    const short* __restrict__ bcur = &Bc[b & 1][0];
    #pragma unroll
    for (int kc = 0; kc < 2; ++kc) {
      #pragma unroll
      for (int nt = 0; nt < 12; ++nt) {
        const short8 bh = *reinterpret_cast<const short8*>(bcur + (kc * 12 + nt) * 512 + l * 8);
        #pragma unroll
        for (int mf = 0; mf < 2; ++mf) {
          acc[mf][nt] = __builtin_amdgcn_mfma_f32_16x16x32_bf16(ah[kc][mf], bh, acc[mf][nt], 0, 0, 0);
          acc[mf][nt] = __builtin_amdgcn_mfma_f32_16x16x32_bf16(al[kc][mf], bh, acc[mf][nt], 0, 0, 0);
        }
      }
    }
    __syncthreads();
  }

  // epilogue: C/D layout col = lane&15, row = (lane>>4)*4 + reg
  #pragma unroll
  for (int mf = 0; mf < 2; ++mf) {
    const long rbase = blkrow + w * 32 + mf * 16 + g * 4;
    #pragma unroll
    for (int nt = 0; nt < 12; ++nt) {
      const int col = nt * 16 + lr;
      const float bb = bias[col];
      #pragma unroll
      for (int i = 0; i < 4; ++i)
        out[(rbase + i) * 192 + col] = acc[mf][nt][i] + bb;
    }
  }
}

// ---------------- 512-col GEMM (GAT Wh) + fused s1/s2, 2-pass, BK=64 ------------
// M=64 per block (wave = 16 rows) -> grid (N/64, 4); A raw prefetch.
__global__ __launch_bounds__(256, 3) void k_gemmW(
    const float* __restrict__ A, const short* __restrict__ Bf2,
    const float* __restrict__ ga,
    float* __restrict__ Wh, float* __restrict__ s1, float* __restrict__ s2,
    const int nb, const int strideA)
{
  __shared__ alignas(16) short Bc[2][16 * 512];   // 2 x 16 KB
  const int tid = threadIdx.x, w = tid >> 6, l = tid & 63;
  const int lr = l & 15, g = l >> 4;
  const long blkrow = (long)blockIdx.x * 64;
  const int cb = blockIdx.y;

  f32x4 acc[8];
  #pragma unroll
  for (int nt = 0; nt < 8; ++nt) acc[nt] = (f32x4){0.f, 0.f, 0.f, 0.f};

  float4 pf[2][2];

  auto LOADA = [&](int b) {
    #pragma unroll
    for (int kc = 0; kc < 2; ++kc) {
      const long r = blkrow + w * 16 + lr;
      const float* __restrict__ src = A + r * (long)strideA + b * 64 + kc * 32 + g * 8;
      pf[kc][0] = *reinterpret_cast<const float4*>(src);
      pf[kc][1] = *reinterpret_cast<const float4*>(src + 4);
    }
  };
  auto STAGE = [&](int buf, int b) {
    const short* __restrict__ bsrc = Bf2 + ((long)cb * nb + b) * 8192;
    #pragma unroll
    for (int i = 0; i < 4; ++i) {
      const int c = w + i * 4;      // 16 x 1KB chunks
      __builtin_amdgcn_global_load_lds(
          (const __attribute__((address_space(1))) void*)(bsrc + c * 512 + l * 8),
          (__attribute__((address_space(3))) void*)(&Bc[buf][c * 512]), 16, 0, 0);
    }
  };

  STAGE(0, 0);
  LOADA(0);
  __syncthreads();

  for (int b = 0; b < nb; ++b) {
    const bool more = (b + 1 < nb);
    if (more) STAGE((b + 1) & 1, b + 1);
    short8 ah[2], al[2];
    #pragma unroll
    for (int kc = 0; kc < 2; ++kc) {
      const float4 v0 = pf[kc][0], v1 = pf[kc][1];
      short h0,l0,h1,l1,h2,l2,h3,l3,h4,l4,h5,l5,h6,l6,h7,l7;
      bsplit(v0.x,h0,l0); bsplit(v0.y,h1,l1); bsplit(v0.z,h2,l2); bsplit(v0.w,h3,l3);
      bsplit(v1.x,h4,l4); bsplit(v1.y,h5,l5); bsplit(v1.z,h6,l6); bsplit(v1.w,h7,l7);
      ah[kc] = (short8){h0,h1,h2,h3,h4,h5,h6,h7};
      al[kc] = (short8){l0,l1,l2,l3,l4,l5,l6,l7};
    }
    if (more) LOADA(b + 1);
    const short* __restrict__ bcur = &Bc[b & 1][0];
    #pragma unroll
    for (int kc = 0; kc < 2; ++kc) {
      #pragma unroll
      for (int nt = 0; nt < 8; ++nt) {
        const short8 bh = *reinterpret_cast<const short8*>(bcur + (kc * 8 + nt) * 512 + l * 8);
        acc[nt] = __builtin_amdgcn_mfma_f32_16x16x32_bf16(ah[kc], bh, acc[nt], 0, 0, 0);
        acc[nt] = __builtin_amdgcn_mfma_f32_16x16x32_bf16(al[kc], bh, acc[nt], 0, 0, 0);
      }
    }
    __syncthreads();
  }

  // epilogue: Wh write + fused s1/s2 (dot over o + 16-lane shuffle reduce)
  const long rbase = blkrow + w * 16 + g * 4;
  #pragma unroll
  for (int nt = 0; nt < 8; ++nt) {
    const int col = cb * 128 + nt * 16 + lr;
    const int u = col >> 6, o = col & 63;
    #pragma unroll
    for (int i = 0; i < 4; ++i)
      Wh[((long)u * N + (rbase + i)) * 64 + o] = acc[nt][i];
  }
  #pragma unroll
  for (int i = 0; i < 4; ++i) {
    const long r = rbase + i;
    #pragma unroll
    for (int uh = 0; uh < 2; ++uh) {
      const int u = cb * 2 + uh;
      float p1 = 0.f, p2 = 0.f;
      #pragma unroll
      for (int nt4 = 0; nt4 < 4; ++nt4) {
        const float v = acc[uh * 4 + nt4][i];
        const int o = nt4 * 16 + lr;
        p1 += v * ga[u * 128 + o];
        p2 += v * ga[u * 128 + 64 + o];
      }
      #pragma unroll
      for (int dd = 8; dd > 0; dd >>= 1) { p1 += __shfl_xor(p1, dd, 64); p2 += __shfl_xor(p2, dd, 64); }
      if (lr == 0) { s1[u * N + r] = p1; s2[u * N + r] = p2; }
    }
  }
}

// ---------------- recurrence over K=20 (gi precomputed, Whh in regs) -------------
__global__ __launch_bounds__(256, 2) void k_recur(
    const float* __restrict__ gi, const float* __restrict__ WhhT,
    const float* __restrict__ bhh, float* __restrict__ rout, const int seq0)
{
  const int tid = threadIdx.x, w = tid >> 6, l = tid & 63;
  const int lseq = blockIdx.x * 4 + w;
  float wr[64], wz[64], wn[64];
  #pragma unroll
  for (int k2 = 0; k2 < 64; ++k2) {
    wr[k2] = WhhT[k2 * 192 + l];
    wz[k2] = WhhT[k2 * 192 + 64 + l];
    wn[k2] = WhhT[k2 * 192 + 128 + l];
  }
  const float bR = bhh[l], bZ = bhh[64 + l], bN = bhh[128 + l];
  const float* __restrict__ grow = gi + (long)lseq * K * 192;
  float h = 0.f, rsum = 0.f;
  float gR = grow[l], gZ = grow[64 + l], gN = grow[128 + l];
  for (int k = 0; k < K; ++k) {
    float nR = 0.f, nZ = 0.f, nN = 0.f;
    if (k + 1 < K) {
      const int off = (k + 1) * 192;
      nR = grow[off + l]; nZ = grow[off + 64 + l]; nN = grow[off + 128 + l];
    }
    float aR = bR, aZ = bZ, aN = bN;
    #pragma unroll
    for (int k2 = 0; k2 < 64; ++k2) {
      const float hk = rdlane(h, k2);
      aR += wr[k2] * hk; aZ += wz[k2] * hk; aN += wn[k2] * hk;
    }
    const float r = sigm(gR + aR);
    const float z = sigm(gZ + aZ);
    const float nn = tanhf(gN + r * aN);
    h = (1.f - z) * nn + z * h;
    rsum += h;
    gR = nR; gZ = nZ; gN = nN;
  }
  const int gseq = seq0 + lseq;
  const int tt = gseq / N, n = gseq % N;
  rout[(n * T + tt) * H + l] = rsum;
}

// ------- fused s-GRU (gx precomputed) + bilinear blend + relu, 4 n per block -----
__global__ __launch_bounds__(256, 2) void k_recur_blend(
    const float* __restrict__ gx, const float* __restrict__ WhhT,
    const float* __restrict__ bhh, const float* __restrict__ q,
    const float* __restrict__ Wt2, const float* __restrict__ bb,
    float* __restrict__ xout)
{
  __shared__ float qs[4][64];
  __shared__ alignas(16) float csh[4][64];
  const int tid = threadIdx.x, w = tid >> 6, l = tid & 63;
  const int n = blockIdx.x * 4 + w;
  // phase A: s-GRU for n (identical math to k_recur_s)
  {
    float wr[64], wz[64], wn[64];
    #pragma unroll
    for (int k2 = 0; k2 < 64; ++k2) {
      wr[k2] = WhhT[k2 * 192 + l];
      wz[k2] = WhhT[k2 * 192 + 64 + l];
      wn[k2] = WhhT[k2 * 192 + 128 + l];
    }
    const float bR = bhh[l], bZ = bhh[64 + l], bN = bhh[128 + l];
    const float* __restrict__ grow = gx + (long)n * T * 192;
    float h = 0.f, cs = 0.f;
    for (int t = 0; t < T; ++t) {
      const float gR = grow[t * 192 + l], gZ = grow[t * 192 + 64 + l], gN = grow[t * 192 + 128 + l];
      float aR = bR, aZ = bZ, aN = bN;
      #pragma unroll
      for (int k2 = 0; k2 < 64; ++k2) {
        const float hk = rdlane(h, k2);
        aR += wr[k2] * hk; aZ += wz[k2] * hk; aN += wn[k2] * hk;
      }
      const float r = sigm(gR + aR), z = sigm(gZ + aZ);
      const float nn = tanhf(gN + r * aN);
      h = (1.f - z) * nn + z * h;
      cs += h;
    }
    csh[w][l] = cs;
    qs[w][l] = q[n * H + l];
  }
  __syncthreads();
  // phase B: blend for the same n, o = lane (same per-(n,o) summation order)
  float acc = bb[l];
  const float4* __restrict__ W4 = reinterpret_cast<const float4*>(Wt2);
  const float4* c4 = reinterpret_cast<const float4*>(&csh[w][0]);
  for (int i = 0; i < 64; ++i) {
    float pa = 0.f;
    #pragma unroll
    for (int j4 = 0; j4 < 16; ++j4) {
      const float4 wv = W4[(i * 16 + j4) * 64 + l];
      const float4 va = c4[j4];
      pa += wv.x * va.x + wv.y * va.y + wv.z * va.z + wv.w * va.w;
    }
    acc += qs[w][i] * pa;
  }
  xout[n * H + l] = fmaxf(acc, 0.f);
}

// ---------------- GAT attention (two-phase, compacted, unrolled gather) ---------
__global__ __launch_bounds__(256) void k_gat_attn(
    const float* __restrict__ Wh, const float* __restrict__ s1,
    const float* __restrict__ s2, const int* __restrict__ nbr,
    const int* __restrict__ deg, const int mode, float* __restrict__ out)
{
  __shared__ float ew[4][CAP];
  __shared__ int nb[4][CAP];
  const int w = threadIdx.x >> 6, lane = threadIdx.x & 63;
  const int row = blockIdx.x * 4 + w;
  const int u = row >> 11;
  const int i = row & (N - 1);
  const int d = deg[i];
  const float su = s1[u * N + i];
  float mx = -1e30f;
  for (int t = lane; t < d; t += 64) {
    const int j = nbr[i * CAP + t];
    float e = su + s2[u * N + j];
    e = e > 0.f ? e : SLOPE * e;
    ew[w][t] = e; nb[w][t] = j;
    mx = fmaxf(mx, e);
  }
  #pragma unroll
  for (int dd = 32; dd > 0; dd >>= 1) mx = fmaxf(mx, __shfl_xor(mx, dd, 64));
  float sm = 0.f;
  for (int t = lane; t < d; t += 64) {
    const float ex = expf(ew[w][t] - mx);
    ew[w][t] = ex;
    sm += ex;
  }
  #pragma unroll
  for (int dd = 32; dd > 0; dd >>= 1) sm += __shfl_xor(sm, dd, 64);
  __syncthreads();
  const float inv = 1.f / sm;
  float a0 = 0.f, a1 = 0.f, a2 = 0.f, a3 = 0.f;
  const float* __restrict__ whb = Wh + (long)u * N * 64 + lane;
  int t = 0;
  for (; t + 4 <= d; t += 4) {
    const float e0 = ew[w][t],     e1 = ew[w][t + 1];
    const float e2 = ew[w][t + 2], e3 = ew[w][t + 3];
    const int j0 = nb[w][t],     j1 = nb[w][t + 1];
    const int j2 = nb[w][t + 2], j3 = nb[w][t + 3];
    a0 += e0 * whb[(long)j0 * 64];
    a1 += e1 * whb[(long)j1 * 64];
    a2 += e2 * whb[(long)j2 * 64];
    a3 += e3 * whb[(long)j3 * 64];
  }
  for (; t < d; ++t) a0 += ew[w][t] * whb[(long)nb[w][t] * 64];
  float acc = ((a0 + a1) + (a2 + a3)) * inv;
  float val;
  if (mode == 0) val = acc > 0.f ? acc : (expf(acc) - 1.f);
  else           val = 1.f / (1.f + expf(-acc));
  out[(long)i * (U * 64) + u * 64 + lane] = val;
}

// ---------------- final projection + sigmoid ----------------
__global__ __launch_bounds__(256) void k_final(
    const float* __restrict__ nz, const float* __restrict__ fw,
    const float* __restrict__ fb, float* __restrict__ out)
{
  const int w = threadIdx.x >> 6, lane = threadIdx.x & 63;
  const int n = blockIdx.x * 4 + w;
  float p = 0.f;
  #pragma unroll
  for (int f = lane; f < 512; f += 64) p += nz[(long)n * 512 + f] * fw[f];
  #pragma unroll
  for (int d = 32; d > 0; d >>= 1) p += __shfl_xor(p, d, 64);
  if (lane == 0) out[n] = 1.f / (1.f + expf(-(p + fb[0])));
}

}  // namespace

extern "C" void kernel_launch(void* const* d_in, const int* in_sizes, int n_in,
                              void* d_out, int out_size, void* d_ws, size_t ws_size,
                              hipStream_t stream)
{
  const float* p     = (const float*)d_in[0];
  const float* m     = (const float*)d_in[1];
  const float* adj   = (const float*)d_in[2];
  const float* Wih_p = (const float*)d_in[3];
  const float* Whh_p = (const float*)d_in[4];
  const float* bih_p = (const float*)d_in[5];
  const float* bhh_p = (const float*)d_in[6];
  const float* Wih_m = (const float*)d_in[7];
  const float* Whh_m = (const float*)d_in[8];
  const float* bih_m = (const float*)d_in[9];
  const float* bhh_m = (const float*)d_in[10];
  const float* Wih_s = (const float*)d_in[11];
  const float* Whh_s = (const float*)d_in[12];
  const float* bih_s = (const float*)d_in[13];
  const float* bhh_s = (const float*)d_in[14];
  // d_in[15..23]: lin-attn weights — unused (softmax over size-1 axis == 1)
  const float* blend_W = (const float*)d_in[24];
  const float* blend_b = (const float*)d_in[25];
  const float* g1W = (const float*)d_in[26];
  const float* g1a = (const float*)d_in[27];
  const float* g2W = (const float*)d_in[28];
  const float* g2a = (const float*)d_in[29];
  const float* finW = (const float*)d_in[30];
  const float* finb = (const float*)d_in[31];

  float* ws = (float*)d_ws;
  float* q    = ws;                    // N*64
  float* rr   = q + N * H;             // N*T*64
  float* c    = rr + N * T * H;        // N*64 (unused after fusion; layout kept)
  float* xb   = c + N * H;             // N*64
  float* Wh1  = xb + N * H;            // U*N*64
  float* s1a  = Wh1 + U * N * 64;      // U*N
  float* s2a  = s1a + U * N;           // U*N
  float* z    = s2a + U * N;           // N*512
  float* Wh2  = z + (long)N * 512;     // U*N*64
  float* s1b  = Wh2 + U * N * 64;      // U*N
  float* s2b  = s1b + U * N;           // U*N
  float* nz   = s2b + U * N;           // N*512
  float* Wt2  = nz + (long)N * 512;    // 64*64*64
  float* gx   = Wt2 + 64 * 64 * 64;    // 10240*192
  float* WhhTm = gx + (long)10240 * 192;   // 64*192
  float* WhhTs = WhhTm + 64 * 192;
  int*   nbr  = (int*)(WhhTs + 64 * 192);  // N*CAP
  int*   deg  = nbr + (long)N * CAP;       // N
  short* BfM  = (short*)(deg + N);         // 8*12288 (hi only)
  short* BfS  = BfM + 8 * 12288;           // 12288
  short* Bf1  = BfS + 12288;               // 4*8192
  short* Bf2  = Bf1 + 4 * 8192;            // 4*8*8192
  float* gi   = (float*)(Bf2 + 4 * 8 * 8192);   // chunked

  // chunk gi to whatever scratch remains (deterministic in ws_size)
  const long avail = (long)(ws_size / 4) - (gi - ws);
  const long total_seqs = (long)T * N;                 // 10240
  long chunk = (avail / ((long)K * 192) / 32) * 32;    // mult of 32 seqs (640 rows)
  if (chunk > total_seqs) chunk = total_seqs;
  if (chunk < 32) chunk = 32;

  k_prep_all<<<N / 4 + 128 + N / 4, 256, 0, stream>>>(
      Wih_m, Whh_m, Wih_s, Whh_s, Whh_p, blend_W, g1W, g2W, adj,
      p, Wih_p, bih_p, bhh_p,
      BfM, BfS, Bf1, Bf2, WhhTm, WhhTs, Wt2, nbr, deg, q);
  for (long s0 = 0; s0 < total_seqs; s0 += chunk) {
    const long cs = (total_seqs - s0) < chunk ? (total_seqs - s0) : chunk;
    const long rows = cs * K;                          // multiple of 640
    k_gemm<<<(int)(rows / 128), 256, 0, stream>>>(m, BfM, bih_m, gi, s0 * K, 8, 512);
    k_recur<<<(int)(cs / 4), 256, 0, stream>>>(gi, WhhTm, bhh_m, rr, (int)s0);
  }
  k_gemm<<<80, 256, 0, stream>>>(rr, BfS, bih_s, gx, 0, 1, 64);
  k_recur_blend<<<N / 4, 256, 0, stream>>>(gx, WhhTs, bhh_s, q, Wt2, blend_b, xb);
  k_gemmW<<<dim3(N / 64, 4), 256, 0, stream>>>(xb, Bf1, g1a, Wh1, s1a, s2a, 1, 64);
  k_gat_attn<<<(U * N) / 4, 256, 0, stream>>>(Wh1, s1a, s2a, nbr, deg, 0, z);
  k_gemmW<<<dim3(N / 64, 4), 256, 0, stream>>>(z, Bf2, g2a, Wh2, s1b, s2b, 8, 512);
  k_gat_attn<<<(U * N) / 4, 256, 0, stream>>>(Wh2, s1b, s2b, nbr, deg, 1, nz);
  k_final<<<N / 4, 256, 0, stream>>>(nz, finW, finb, (float*)d_out);
}

// Round 18
// 447.458 us; speedup vs baseline: 1.0519x; 1.0519x over previous
//
#include <hip/hip_runtime.h>
#include <math.h>

namespace {

constexpr int T = 5, N = 2048, K = 20, E = 512;
constexpr int H = 64, U = 8;
constexpr int CAP = 512;           // max neighbors kept (measured mean ~103)
constexpr float SLOPE = 0.01f;

typedef __attribute__((ext_vector_type(8))) short short8;
typedef __attribute__((ext_vector_type(4))) float f32x4;

__device__ inline float sigm(float x) { return 1.0f / (1.0f + expf(-x)); }

// split fp32 -> bf16 hi + bf16 lo (truncation; x ~= hi+lo with rel err <= 2^-16)
__device__ inline void bsplit(float x, short& hi, short& lo) {
  unsigned u = __float_as_uint(x);
  hi = (short)(u >> 16);
  float r = x - __uint_as_float(u & 0xFFFF0000u);
  lo = (short)(__float_as_uint(r) >> 16);
}

__device__ inline float rdlane(float v, int lane) {
  return __int_as_float(__builtin_amdgcn_readlane(__float_as_int(v), lane));
}

// 512-col fragment pack ([U][Ksz][64] -> hi-only fragment blocks, BK=64)
__device__ inline void pack512(const float* __restrict__ src, short* __restrict__ dst,
                               const int Ksz, const int pb, const int nPB) {
  const int nb64 = Ksz >> 6;
  const int total = 8 * Ksz * 64;
  for (int idx = threadIdx.x + pb * 256; idx < total; idx += 256 * nPB) {
    const int u = idx / (Ksz * 64), rem = idx - u * Ksz * 64;
    const int f = rem >> 6, o = rem & 63;
    const int col = u * 64 + o;
    const long base = ((long)(col >> 7) * nb64 + (f >> 6)) * 8192
                    + (((f >> 5) & 1) * 8 + ((col >> 4) & 7)) * 512
                    + ((f >> 3) & 3) * 128 + (col & 15) * 8 + (f & 7);
    dst[base] = (short)(__float_as_uint(src[idx]) >> 16);
  }
}

// ---------------- mega-prep: compact (512) + packs (128) + p-GRU (512) ----------
__global__ __launch_bounds__(256) void k_prep_all(
    const float* __restrict__ WihM, const float* __restrict__ WhhM,
    const float* __restrict__ WihS, const float* __restrict__ WhhS,
    const float* __restrict__ WhhP, const float* __restrict__ Wb,
    const float* __restrict__ g1W, const float* __restrict__ g2W,
    const float* __restrict__ adj,
    const float* __restrict__ p, const float* __restrict__ WihP,
    const float* __restrict__ bihP, const float* __restrict__ bhhP,
    short* __restrict__ BfM, short* __restrict__ BfS,
    short* __restrict__ Bf1, short* __restrict__ Bf2,
    float* __restrict__ WhhTm, float* __restrict__ WhhTs,
    float* __restrict__ Wt2, int* __restrict__ nbr, int* __restrict__ deg,
    float* __restrict__ q)
{
  const int b = blockIdx.x;
  if (b < N / 4) {
    const int w = threadIdx.x >> 6, lane = threadIdx.x & 63;
    const int i = b * 4 + w;
    int base = 0;
    for (int j0 = 0; j0 < N; j0 += 64) {
      const float v = adj[(long)i * N + j0 + lane];
      const unsigned long long mask = __ballot(v > 0.f);
      const int pre = __popcll(mask & ((1ull << lane) - 1ull));
      if (v > 0.f && base + pre < CAP) nbr[i * CAP + base + pre] = j0 + lane;
      base += __popcll(mask);
    }
    if (lane == 0) deg[i] = base < CAP ? base : CAP;
    return;
  }
  if (b < N / 4 + 128) {
    const int pb = b - N / 4;        // 0..127
    constexpr int NPB = 128;
    for (int idx = threadIdx.x + pb * 256; idx < 192 * 512; idx += 256 * NPB) {
      const int o = idx >> 9, k = idx & 511;
      const long base = (long)(k >> 6) * 12288 + (((k >> 5) & 1) * 12 + (o >> 4)) * 512
                      + ((k >> 3) & 3) * 128 + (o & 15) * 8 + (k & 7);
      BfM[base] = (short)(__float_as_uint(WihM[idx]) >> 16);
    }
    for (int idx = threadIdx.x + pb * 256; idx < 192 * 64; idx += 256 * NPB) {
      const int o = idx >> 6, k = idx & 63;
      const long base = (((k >> 5) & 1) * 12 + (o >> 4)) * 512
                      + ((k >> 3) & 3) * 128 + (o & 15) * 8 + (k & 7);
      BfS[base] = (short)(__float_as_uint(WihS[idx]) >> 16);
    }
    for (int idx = threadIdx.x + pb * 256; idx < 64 * 192; idx += 256 * NPB) {
      const int k2 = idx / 192, row = idx % 192;
      WhhTm[idx] = WhhM[row * 64 + k2];
      WhhTs[idx] = WhhS[row * 64 + k2];
    }
    for (int idx = threadIdx.x + pb * 256; idx < 64 * 64 * 64; idx += 256 * NPB) {
      const int o = idx >> 12, rem = idx & 4095, i = rem >> 6, j = rem & 63;
      Wt2[((i * 16 + (j >> 2)) * 64 + o) * 4 + (j & 3)] = Wb[(o * 64 + i) * 64 + j];
    }
    pack512(g1W, Bf1, 64, pb, NPB);
    pack512(g2W, Bf2, 512, pb, NPB);
    return;
  }
  // p-GRU: 4 seqs per block, Whh rows read directly (per-lane contiguous)
  const int rb = b - (N / 4 + 128);
  const int w = threadIdx.x >> 6, l = threadIdx.x & 63;
  const int n = rb * 4 + w;
  float wr[64], wz[64], wn[64];
  #pragma unroll
  for (int k2 = 0; k2 < 64; ++k2) {
    wr[k2] = WhhP[l * 64 + k2];
    wz[k2] = WhhP[(64 + l) * 64 + k2];
    wn[k2] = WhhP[(128 + l) * 64 + k2];
  }
  float iR[3], iZ[3], iN[3];
  #pragma unroll
  for (int c = 0; c < 3; ++c) {
    iR[c] = WihP[l * 3 + c];
    iZ[c] = WihP[(64 + l) * 3 + c];
    iN[c] = WihP[(128 + l) * 3 + c];
  }
  const float biR = bihP[l], biZ = bihP[64 + l], biN = bihP[128 + l];
  const float bhR = bhhP[l], bhZ = bhhP[64 + l], bhN = bhhP[128 + l];
  float h = 0.f, qs = 0.f;
  for (int t = 0; t < T; ++t) {
    const float x0 = p[n * 15 + t * 3], x1 = p[n * 15 + t * 3 + 1], x2 = p[n * 15 + t * 3 + 2];
    const float gR = biR + iR[0] * x0 + iR[1] * x1 + iR[2] * x2;
    const float gZ = biZ + iZ[0] * x0 + iZ[1] * x1 + iZ[2] * x2;
    const float gN = biN + iN[0] * x0 + iN[1] * x1 + iN[2] * x2;
    float aR = bhR, aZ = bhZ, aN = bhN;
    #pragma unroll
    for (int k2 = 0; k2 < 64; ++k2) {
      const float hk = rdlane(h, k2);
      aR += wr[k2] * hk; aZ += wz[k2] * hk; aN += wn[k2] * hk;
    }
    const float r = sigm(gR + aR), z = sigm(gZ + aZ);
    const float nn = tanhf(gN + r * aN);
    h = (1.f - z) * nn + z * h;
    qs += h;
  }
  q[n * H + l] = qs;
}

// ---------------- 192-col GEMM: [rows,Ksz] x [Ksz,192] + bias, 2-pass -----------
// C = (Ah+Al)·Bh. BK=64 B-dbuf + A raw-float4 prefetch (bsplit at use).
__global__ __launch_bounds__(256, 2) void k_gemm(
    const float* __restrict__ A, const short* __restrict__ Bf,
    const float* __restrict__ bias, float* __restrict__ out,
    const long row0, const int nb, const int strideA)
{
  __shared__ alignas(16) short Bc[2][24 * 512];   // 2 x 24 KB
  const int tid = threadIdx.x, w = tid >> 6, l = tid & 63;
  const int lr = l & 15, g = l >> 4;
  const long blkrow = (long)blockIdx.x * 128;

  f32x4 acc[2][12];
  #pragma unroll
  for (int mf = 0; mf < 2; ++mf)
    #pragma unroll
    for (int nt = 0; nt < 12; ++nt) acc[mf][nt] = (f32x4){0.f, 0.f, 0.f, 0.f};

  float4 pf[2][2][2];   // [kc][mf][half] raw A prefetch

  auto LOADA = [&](int b) {
    #pragma unroll
    for (int kc = 0; kc < 2; ++kc)
      #pragma unroll
      for (int mf = 0; mf < 2; ++mf) {
        const long r = blkrow + w * 32 + mf * 16 + lr;
        const float* __restrict__ src = A + (row0 + r) * (long)strideA + b * 64 + kc * 32 + g * 8;
        pf[kc][mf][0] = *reinterpret_cast<const float4*>(src);
        pf[kc][mf][1] = *reinterpret_cast<const float4*>(src + 4);
      }
  };
  auto STAGE = [&](int buf, int b) {
    const short* __restrict__ bsrc = Bf + (long)b * 12288;
    #pragma unroll
    for (int i = 0; i < 6; ++i) {
      const int c = w + i * 4;      // 24 x 1KB chunks
      __builtin_amdgcn_global_load_lds(
          (const __attribute__((address_space(1))) void*)(bsrc + c * 512 + l * 8),
          (__attribute__((address_space(3))) void*)(&Bc[buf][c * 512]), 16, 0, 0);
    }
  };

  STAGE(0, 0);
  LOADA(0);
  __syncthreads();

  for (int b = 0; b < nb; ++b) {
    const bool more = (b + 1 < nb);
    if (more) STAGE((b + 1) & 1, b + 1);
    // convert current prefetch to fragments, then immediately issue next loads
    short8 ah[2][2], al[2][2];
    #pragma unroll
    for (int kc = 0; kc < 2; ++kc)
      #pragma unroll
      for (int mf = 0; mf < 2; ++mf) {
        const float4 v0 = pf[kc][mf][0], v1 = pf[kc][mf][1];
        short h0,l0,h1,l1,h2,l2,h3,l3,h4,l4,h5,l5,h6,l6,h7,l7;
        bsplit(v0.x,h0,l0); bsplit(v0.y,h1,l1); bsplit(v0.z,h2,l2); bsplit(v0.w,h3,l3);
        bsplit(v1.x,h4,l4); bsplit(v1.y,h5,l5); bsplit(v1.z,h6,l6); bsplit(v1.w,h7,l7);
        ah[kc][mf] = (short8){h0,h1,h2,h3,h4,h5,h6,h7};
        al[kc][mf] = (short8){l0,l1,l2,l3,l4,l5,l6,l7};
      }
    if (more) LOADA(b + 1);
    const short* __restrict__ bcur = &Bc[b & 1][0];
    #pragma unroll
    for (int kc = 0; kc < 2; ++kc) {
      #pragma unroll
      for (int nt = 0; nt < 12; ++nt) {
        const short8 bh = *reinterpret_cast<const short8*>(bcur + (kc * 12 + nt) * 512 + l * 8);
        #pragma unroll
        for (int mf = 0; mf < 2; ++mf) {
          acc[mf][nt] = __builtin_amdgcn_mfma_f32_16x16x32_bf16(ah[kc][mf], bh, acc[mf][nt], 0, 0, 0);
          acc[mf][nt] = __builtin_amdgcn_mfma_f32_16x16x32_bf16(al[kc][mf], bh, acc[mf][nt], 0, 0, 0);
        }
      }
    }
    __syncthreads();
  }

  // epilogue: C/D layout col = lane&15, row = (lane>>4)*4 + reg
  #pragma unroll
  for (int mf = 0; mf < 2; ++mf) {
    const long rbase = blkrow + w * 32 + mf * 16 + g * 4;
    #pragma unroll
    for (int nt = 0; nt < 12; ++nt) {
      const int col = nt * 16 + lr;
      const float bb = bias[col];
      #pragma unroll
      for (int i = 0; i < 4; ++i)
        out[(rbase + i) * 192 + col] = acc[mf][nt][i] + bb;
    }
  }
}

// ---------------- 512-col GEMM (GAT Wh) + fused s1/s2, 2-pass, BK=64 ------------
// M=64 per block (wave = 16 rows) -> grid (N/64, 4); A raw prefetch.
__global__ __launch_bounds__(256, 3) void k_gemmW(
    const float* __restrict__ A, const short* __restrict__ Bf2,
    const float* __restrict__ ga,
    float* __restrict__ Wh, float* __restrict__ s1, float* __restrict__ s2,
    const int nb, const int strideA)
{
  __shared__ alignas(16) short Bc[2][16 * 512];   // 2 x 16 KB
  const int tid = threadIdx.x, w = tid >> 6, l = tid & 63;
  const int lr = l & 15, g = l >> 4;
  const long blkrow = (long)blockIdx.x * 64;
  const int cb = blockIdx.y;

  f32x4 acc[8];
  #pragma unroll
  for (int nt = 0; nt < 8; ++nt) acc[nt] = (f32x4){0.f, 0.f, 0.f, 0.f};

  float4 pf[2][2];

  auto LOADA = [&](int b) {
    #pragma unroll
    for (int kc = 0; kc < 2; ++kc) {
      const long r = blkrow + w * 16 + lr;
      const float* __restrict__ src = A + r * (long)strideA + b * 64 + kc * 32 + g * 8;
      pf[kc][0] = *reinterpret_cast<const float4*>(src);
      pf[kc][1] = *reinterpret_cast<const float4*>(src + 4);
    }
  };
  auto STAGE = [&](int buf, int b) {
    const short* __restrict__ bsrc = Bf2 + ((long)cb * nb + b) * 8192;
    #pragma unroll
    for (int i = 0; i < 4; ++i) {
      const int c = w + i * 4;      // 16 x 1KB chunks
      __builtin_amdgcn_global_load_lds(
          (const __attribute__((address_space(1))) void*)(bsrc + c * 512 + l * 8),
          (__attribute__((address_space(3))) void*)(&Bc[buf][c * 512]), 16, 0, 0);
    }
  };

  STAGE(0, 0);
  LOADA(0);
  __syncthreads();

  for (int b = 0; b < nb; ++b) {
    const bool more = (b + 1 < nb);
    if (more) STAGE((b + 1) & 1, b + 1);
    short8 ah[2], al[2];
    #pragma unroll
    for (int kc = 0; kc < 2; ++kc) {
      const float4 v0 = pf[kc][0], v1 = pf[kc][1];
      short h0,l0,h1,l1,h2,l2,h3,l3,h4,l4,h5,l5,h6,l6,h7,l7;
      bsplit(v0.x,h0,l0); bsplit(v0.y,h1,l1); bsplit(v0.z,h2,l2); bsplit(v0.w,h3,l3);
      bsplit(v1.x,h4,l4); bsplit(v1.y,h5,l5); bsplit(v1.z,h6,l6); bsplit(v1.w,h7,l7);
      ah[kc] = (short8){h0,h1,h2,h3,h4,h5,h6,h7};
      al[kc] = (short8){l0,l1,l2,l3,l4,l5,l6,l7};
    }
    if (more) LOADA(b + 1);
    const short* __restrict__ bcur = &Bc[b & 1][0];
    #pragma unroll
    for (int kc = 0; kc < 2; ++kc) {
      #pragma unroll
      for (int nt = 0; nt < 8; ++nt) {
        const short8 bh = *reinterpret_cast<const short8*>(bcur + (kc * 8 + nt) * 512 + l * 8);
        acc[nt] = __builtin_amdgcn_mfma_f32_16x16x32_bf16(ah[kc], bh, acc[nt], 0, 0, 0);
        acc[nt] = __builtin_amdgcn_mfma_f32_16x16x32_bf16(al[kc], bh, acc[nt], 0, 0, 0);
      }
    }
    __syncthreads();
  }

  // epilogue: Wh write + fused s1/s2 (dot over o + 16-lane shuffle reduce)
  const long rbase = blkrow + w * 16 + g * 4;
  #pragma unroll
  for (int nt = 0; nt < 8; ++nt) {
    const int col = cb * 128 + nt * 16 + lr;
    const int u = col >> 6, o = col & 63;
    #pragma unroll
    for (int i = 0; i < 4; ++i)
      Wh[((long)u * N + (rbase + i)) * 64 + o] = acc[nt][i];
  }
  #pragma unroll
  for (int i = 0; i < 4; ++i) {
    const long r = rbase + i;
    #pragma unroll
    for (int uh = 0; uh < 2; ++uh) {
      const int u = cb * 2 + uh;
      float p1 = 0.f, p2 = 0.f;
      #pragma unroll
      for (int nt4 = 0; nt4 < 4; ++nt4) {
        const float v = acc[uh * 4 + nt4][i];
        const int o = nt4 * 16 + lr;
        p1 += v * ga[u * 128 + o];
        p2 += v * ga[u * 128 + 64 + o];
      }
      #pragma unroll
      for (int dd = 8; dd > 0; dd >>= 1) { p1 += __shfl_xor(p1, dd, 64); p2 += __shfl_xor(p2, dd, 64); }
      if (lr == 0) { s1[u * N + r] = p1; s2[u * N + r] = p2; }
    }
  }
}

// ---------------- recurrence over K=20 (gi precomputed, Whh in regs) -------------
__global__ __launch_bounds__(256, 2) void k_recur(
    const float* __restrict__ gi, const float* __restrict__ WhhT,
    const float* __restrict__ bhh, float* __restrict__ rout, const int seq0)
{
  const int tid = threadIdx.x, w = tid >> 6, l = tid & 63;
  const int lseq = blockIdx.x * 4 + w;
  float wr[64], wz[64], wn[64];
  #pragma unroll
  for (int k2 = 0; k2 < 64; ++k2) {
    wr[k2] = WhhT[k2 * 192 + l];
    wz[k2] = WhhT[k2 * 192 + 64 + l];
    wn[k2] = WhhT[k2 * 192 + 128 + l];
  }
  const float bR = bhh[l], bZ = bhh[64 + l], bN = bhh[128 + l];
  const float* __restrict__ grow = gi + (long)lseq * K * 192;
  float h = 0.f, rsum = 0.f;
  float gR = grow[l], gZ = grow[64 + l], gN = grow[128 + l];
  for (int k = 0; k < K; ++k) {
    float nR = 0.f, nZ = 0.f, nN = 0.f;
    if (k + 1 < K) {
      const int off = (k + 1) * 192;
      nR = grow[off + l]; nZ = grow[off + 64 + l]; nN = grow[off + 128 + l];
    }
    float aR = bR, aZ = bZ, aN = bN;
    #pragma unroll
    for (int k2 = 0; k2 < 64; ++k2) {
      const float hk = rdlane(h, k2);
      aR += wr[k2] * hk; aZ += wz[k2] * hk; aN += wn[k2] * hk;
    }
    const float r = sigm(gR + aR);
    const float z = sigm(gZ + aZ);
    const float nn = tanhf(gN + r * aN);
    h = (1.f - z) * nn + z * h;
    rsum += h;
    gR = nR; gZ = nZ; gN = nN;
  }
  const int gseq = seq0 + lseq;
  const int tt = gseq / N, n = gseq % N;
  rout[(n * T + tt) * H + l] = rsum;
}

// ---------------- s-GRU: gx precomputed (bias included), Whh in regs, T=5 --------
__global__ __launch_bounds__(256, 2) void k_recur_s(
    const float* __restrict__ gx, const float* __restrict__ WhhT,
    const float* __restrict__ bhh, float* __restrict__ c)
{
  const int tid = threadIdx.x, w = tid >> 6, l = tid & 63;
  const int n = blockIdx.x * 4 + w;
  float wr[64], wz[64], wn[64];
  #pragma unroll
  for (int k2 = 0; k2 < 64; ++k2) {
    wr[k2] = WhhT[k2 * 192 + l];
    wz[k2] = WhhT[k2 * 192 + 64 + l];
    wn[k2] = WhhT[k2 * 192 + 128 + l];
  }
  const float bR = bhh[l], bZ = bhh[64 + l], bN = bhh[128 + l];
  const float* __restrict__ grow = gx + (long)n * T * 192;
  float h = 0.f, cs = 0.f;
  for (int t = 0; t < T; ++t) {
    const float gR = grow[t * 192 + l], gZ = grow[t * 192 + 64 + l], gN = grow[t * 192 + 128 + l];
    float aR = bR, aZ = bZ, aN = bN;
    #pragma unroll
    for (int k2 = 0; k2 < 64; ++k2) {
      const float hk = rdlane(h, k2);
      aR += wr[k2] * hk; aZ += wz[k2] * hk; aN += wn[k2] * hk;
    }
    const float r = sigm(gR + aR), z = sigm(gZ + aZ);
    const float nn = tanhf(gN + r * aN);
    h = (1.f - z) * nn + z * h;
    cs += h;
  }
  c[n * H + l] = cs;
}

// ---------------- bilinear blend + relu (transposed W, 8 n per block) -----------
__global__ __launch_bounds__(256) void k_blend(
    const float* __restrict__ q, const float* __restrict__ c,
    const float* __restrict__ Wt2, const float* __restrict__ b,
    float* __restrict__ xout)
{
  __shared__ float qs[8][64];
  __shared__ alignas(16) float cs[8][64];
  const int tid = threadIdx.x;
  const int o = tid & 63, grp = tid >> 6;
  const int n0 = blockIdx.x * 8;
  for (int idx = tid; idx < 512; idx += 256) {
    qs[idx >> 6][idx & 63] = q[(n0 + (idx >> 6)) * 64 + (idx & 63)];
    cs[idx >> 6][idx & 63] = c[(n0 + (idx >> 6)) * 64 + (idx & 63)];
  }
  __syncthreads();
  const int na = grp * 2, nb = na + 1;
  float acca = b[o], accb = b[o];
  const float4* __restrict__ W4 = reinterpret_cast<const float4*>(Wt2);
  const float4* ca4 = reinterpret_cast<const float4*>(&cs[na][0]);
  const float4* cb4 = reinterpret_cast<const float4*>(&cs[nb][0]);
  for (int i = 0; i < 64; ++i) {
    float pa = 0.f, pb = 0.f;
    #pragma unroll
    for (int j4 = 0; j4 < 16; ++j4) {
      const float4 wv = W4[(i * 16 + j4) * 64 + o];
      const float4 va = ca4[j4], vb = cb4[j4];
      pa += wv.x * va.x + wv.y * va.y + wv.z * va.z + wv.w * va.w;
      pb += wv.x * vb.x + wv.y * vb.y + wv.z * vb.z + wv.w * vb.w;
    }
    acca += qs[na][i] * pa;
    accb += qs[nb][i] * pb;
  }
  xout[(n0 + na) * 64 + o] = fmaxf(acca, 0.f);
  xout[(n0 + nb) * 64 + o] = fmaxf(accb, 0.f);
}

// ---------------- GAT attention (two-phase, compacted, unrolled gather) ---------
__global__ __launch_bounds__(256) void k_gat_attn(
    const float* __restrict__ Wh, const float* __restrict__ s1,
    const float* __restrict__ s2, const int* __restrict__ nbr,
    const int* __restrict__ deg, const int mode, float* __restrict__ out)
{
  __shared__ float ew[4][CAP];
  __shared__ int nb[4][CAP];
  const int w = threadIdx.x >> 6, lane = threadIdx.x & 63;
  const int row = blockIdx.x * 4 + w;
  const int u = row >> 11;
  const int i = row & (N - 1);
  const int d = deg[i];
  const float su = s1[u * N + i];
  float mx = -1e30f;
  for (int t = lane; t < d; t += 64) {
    const int j = nbr[i * CAP + t];
    float e = su + s2[u * N + j];
    e = e > 0.f ? e : SLOPE * e;
    ew[w][t] = e; nb[w][t] = j;
    mx = fmaxf(mx, e);
  }
  #pragma unroll
  for (int dd = 32; dd > 0; dd >>= 1) mx = fmaxf(mx, __shfl_xor(mx, dd, 64));
  float sm = 0.f;
  for (int t = lane; t < d; t += 64) {
    const float ex = expf(ew[w][t] - mx);
    ew[w][t] = ex;
    sm += ex;
  }
  #pragma unroll
  for (int dd = 32; dd > 0; dd >>= 1) sm += __shfl_xor(sm, dd, 64);
  __syncthreads();
  const float inv = 1.f / sm;
  float a0 = 0.f, a1 = 0.f, a2 = 0.f, a3 = 0.f;
  const float* __restrict__ whb = Wh + (long)u * N * 64 + lane;
  int t = 0;
  for (; t + 4 <= d; t += 4) {
    const float e0 = ew[w][t],     e1 = ew[w][t + 1];
    const float e2 = ew[w][t + 2], e3 = ew[w][t + 3];
    const int j0 = nb[w][t],     j1 = nb[w][t + 1];
    const int j2 = nb[w][t + 2], j3 = nb[w][t + 3];
    a0 += e0 * whb[(long)j0 * 64];
    a1 += e1 * whb[(long)j1 * 64];
    a2 += e2 * whb[(long)j2 * 64];
    a3 += e3 * whb[(long)j3 * 64];
  }
  for (; t < d; ++t) a0 += ew[w][t] * whb[(long)nb[w][t] * 64];
  float acc = ((a0 + a1) + (a2 + a3)) * inv;
  float val;
  if (mode == 0) val = acc > 0.f ? acc : (expf(acc) - 1.f);
  else           val = 1.f / (1.f + expf(-acc));
  out[(long)i * (U * 64) + u * 64 + lane] = val;
}

// ---------------- final projection + sigmoid ----------------
__global__ __launch_bounds__(256) void k_final(
    const float* __restrict__ nz, const float* __restrict__ fw,
    const float* __restrict__ fb, float* __restrict__ out)
{
  const int w = threadIdx.x >> 6, lane = threadIdx.x & 63;
  const int n = blockIdx.x * 4 + w;
  float p = 0.f;
  #pragma unroll
  for (int f = lane; f < 512; f += 64) p += nz[(long)n * 512 + f] * fw[f];
  #pragma unroll
  for (int d = 32; d > 0; d >>= 1) p += __shfl_xor(p, d, 64);
  if (lane == 0) out[n] = 1.f / (1.f + expf(-(p + fb[0])));
}

}  // namespace

extern "C" void kernel_launch(void* const* d_in, const int* in_sizes, int n_in,
                              void* d_out, int out_size, void* d_ws, size_t ws_size,
                              hipStream_t stream)
{
  const float* p     = (const float*)d_in[0];
  const float* m     = (const float*)d_in[1];
  const float* adj   = (const float*)d_in[2];
  const float* Wih_p = (const float*)d_in[3];
  const float* Whh_p = (const float*)d_in[4];
  const float* bih_p = (const float*)d_in[5];
  const float* bhh_p = (const float*)d_in[6];
  const float* Wih_m = (const float*)d_in[7];
  const float* Whh_m = (const float*)d_in[8];
  const float* bih_m = (const float*)d_in[9];
  const float* bhh_m = (const float*)d_in[10];
  const float* Wih_s = (const float*)d_in[11];
  const float* Whh_s = (const float*)d_in[12];
  const float* bih_s = (const float*)d_in[13];
  const float* bhh_s = (const float*)d_in[14];
  // d_in[15..23]: lin-attn weights — unused (softmax over size-1 axis == 1)
  const float* blend_W = (const float*)d_in[24];
  const float* blend_b = (const float*)d_in[25];
  const float* g1W = (const float*)d_in[26];
  const float* g1a = (const float*)d_in[27];
  const float* g2W = (const float*)d_in[28];
  const float* g2a = (const float*)d_in[29];
  const float* finW = (const float*)d_in[30];
  const float* finb = (const float*)d_in[31];

  float* ws = (float*)d_ws;
  float* q    = ws;                    // N*64
  float* rr   = q + N * H;             // N*T*64
  float* c    = rr + N * T * H;        // N*64
  float* xb   = c + N * H;             // N*64
  float* Wh1  = xb + N * H;            // U*N*64
  float* s1a  = Wh1 + U * N * 64;      // U*N
  float* s2a  = s1a + U * N;           // U*N
  float* z    = s2a + U * N;           // N*512
  float* Wh2  = z + (long)N * 512;     // U*N*64
  float* s1b  = Wh2 + U * N * 64;      // U*N
  float* s2b  = s1b + U * N;           // U*N
  float* nz   = s2b + U * N;           // N*512
  float* Wt2  = nz + (long)N * 512;    // 64*64*64
  float* gx   = Wt2 + 64 * 64 * 64;    // 10240*192
  float* WhhTm = gx + (long)10240 * 192;   // 64*192
  float* WhhTs = WhhTm + 64 * 192;
  int*   nbr  = (int*)(WhhTs + 64 * 192);  // N*CAP
  int*   deg  = nbr + (long)N * CAP;       // N
  short* BfM  = (short*)(deg + N);         // 8*12288 (hi only)
  short* BfS  = BfM + 8 * 12288;           // 12288
  short* Bf1  = BfS + 12288;               // 4*8192
  short* Bf2  = Bf1 + 4 * 8192;            // 4*8*8192
  float* gi   = (float*)(Bf2 + 4 * 8 * 8192);   // chunked

  // chunk gi to whatever scratch remains (deterministic in ws_size)
  const long avail = (long)(ws_size / 4) - (gi - ws);
  const long total_seqs = (long)T * N;                 // 10240
  long chunk = (avail / ((long)K * 192) / 32) * 32;    // mult of 32 seqs (640 rows)
  if (chunk > total_seqs) chunk = total_seqs;
  if (chunk < 32) chunk = 32;

  k_prep_all<<<N / 4 + 128 + N / 4, 256, 0, stream>>>(
      Wih_m, Whh_m, Wih_s, Whh_s, Whh_p, blend_W, g1W, g2W, adj,
      p, Wih_p, bih_p, bhh_p,
      BfM, BfS, Bf1, Bf2, WhhTm, WhhTs, Wt2, nbr, deg, q);
  for (long s0 = 0; s0 < total_seqs; s0 += chunk) {
    const long cs = (total_seqs - s0) < chunk ? (total_seqs - s0) : chunk;
    const long rows = cs * K;                          // multiple of 640
    k_gemm<<<(int)(rows / 128), 256, 0, stream>>>(m, BfM, bih_m, gi, s0 * K, 8, 512);
    k_recur<<<(int)(cs / 4), 256, 0, stream>>>(gi, WhhTm, bhh_m, rr, (int)s0);
  }
  k_gemm<<<80, 256, 0, stream>>>(rr, BfS, bih_s, gx, 0, 1, 64);
  k_recur_s<<<N / 4, 256, 0, stream>>>(gx, WhhTs, bhh_s, c);
  k_blend<<<N / 8, 256, 0, stream>>>(q, c, Wt2, blend_b, xb);
  k_gemmW<<<dim3(N / 64, 4), 256, 0, stream>>>(xb, Bf1, g1a, Wh1, s1a, s2a, 1, 64);
  k_gat_attn<<<(U * N) / 4, 256, 0, stream>>>(Wh1, s1a, s2a, nbr, deg, 0, z);
  k_gemmW<<<dim3(N / 64, 4), 256, 0, stream>>>(z, Bf2, g2a, Wh2, s1b, s2b, 8, 512);
  k_gat_attn<<<(U * N) / 4, 256, 0, stream>>>(Wh2, s1b, s2b, nbr, deg, 1, nz);
  k_final<<<N / 4, 256, 0, stream>>>(nz, finW, finb, (float*)d_out);
}